// Round 1
// baseline (1068.266 us; speedup 1.0000x reference)
//
#include <hip/hip_runtime.h>
#include <hip/hip_fp16.h>

typedef float    f32x4 __attribute__((ext_vector_type(4)));
typedef _Float16 f16x8 __attribute__((ext_vector_type(8)));

__device__ __forceinline__ float sigmoidf_(float x) { return 1.f / (1.f + __expf(-x)); }
// tanh via exp(2x), safe at +/-inf: large x -> 1, very negative -> -1
__device__ __forceinline__ float tanhf_(float x) { float e = __expf(2.f * x); return 1.f - 2.f / (e + 1.f); }
__device__ __forceinline__ float lrelu_(float v) { return v > 0.f ? v : 0.01f * v; }

__device__ __forceinline__ f16x8 cvt8(const float* p) {
    const f32x4* q = (const f32x4*)p;
    f32x4 a = q[0], b = q[1];
    f16x8 v;
    v[0] = (_Float16)a[0]; v[1] = (_Float16)a[1]; v[2] = (_Float16)a[2]; v[3] = (_Float16)a[3];
    v[4] = (_Float16)b[0]; v[5] = (_Float16)b[1]; v[6] = (_Float16)b[2]; v[7] = (_Float16)b[3];
    return v;
}

// ---------------- LayerNorm + cast to f16, row-major [NT][128] ----------------
// block 256: 16 rows, 16 threads/row, 8 elems/thread
__global__ __launch_bounds__(256) void k_ln(const float* __restrict__ x,
                                            const float* __restrict__ g,
                                            const float* __restrict__ b,
                                            _Float16* __restrict__ xn)
{
    int tid = threadIdx.x;
    int r = tid >> 4, i = tid & 15;
    size_t row = (size_t)blockIdx.x * 16 + r;
    const f32x4* xp = (const f32x4*)(x + row * 128 + i * 8);
    f32x4 a0 = xp[0], a1 = xp[1];
    float v0=a0[0], v1=a0[1], v2=a0[2], v3=a0[3], v4=a1[0], v5=a1[1], v6=a1[2], v7=a1[3];
    float s  = v0+v1+v2+v3+v4+v5+v6+v7;
    float s2 = v0*v0+v1*v1+v2*v2+v3*v3+v4*v4+v5*v5+v6*v6+v7*v7;
#pragma unroll
    for (int m = 1; m <= 8; m <<= 1) { s += __shfl_xor(s, m); s2 += __shfl_xor(s2, m); }
    float mu  = s * (1.f / 128.f);
    float var = s2 * (1.f / 128.f) - mu * mu;
    float rs  = rsqrtf(var + 1e-5f);
    const f32x4* gp = (const f32x4*)(g + i * 8);
    const f32x4* bp = (const f32x4*)(b + i * 8);
    f32x4 g0 = gp[0], g1 = gp[1], bb0 = bp[0], bb1 = bp[1];
    f16x8 o;
    o[0] = (_Float16)((v0 - mu) * rs * g0[0] + bb0[0]);
    o[1] = (_Float16)((v1 - mu) * rs * g0[1] + bb0[1]);
    o[2] = (_Float16)((v2 - mu) * rs * g0[2] + bb0[2]);
    o[3] = (_Float16)((v3 - mu) * rs * g0[3] + bb0[3]);
    o[4] = (_Float16)((v4 - mu) * rs * g1[0] + bb1[0]);
    o[5] = (_Float16)((v5 - mu) * rs * g1[1] + bb1[1]);
    o[6] = (_Float16)((v6 - mu) * rs * g1[2] + bb1[2]);
    o[7] = (_Float16)((v7 - mu) * rs * g1[3] + bb1[3]);
    *(f16x8*)(xn + row * 128 + i * 8) = o;
}

// ---------------- Fused GRU layer ----------------
// 512 thr = 8 waves; block owns 16 rows x 64 steps. Wave w owns hidden units
// [16w,16w+16) => gate columns u, u+128, u+256. W_ih/W_hh held as f16 MFMA
// B-fragments in registers (96 VGPR/lane). h fp32 in registers (C-layout is
// time-invariant); re-shaped to A-frags via small double-buffered LDS tile.
__global__ __launch_bounds__(512, 2) void k_gru(const _Float16* __restrict__ xin,
                                                const float* __restrict__ W_ih,
                                                const float* __restrict__ W_hh,
                                                const float* __restrict__ b_ih,
                                                const float* __restrict__ b_hh,
                                                _Float16* __restrict__ hout,
                                                float* __restrict__ es)
{
    __shared__ __align__(16) _Float16 hbuf[2][16 * 136];   // row stride 136 to dodge bank conflicts
    int tid = threadIdx.x;
    int w = tid >> 6, lane = tid & 63;
    int ul = lane & 15, q = lane >> 4;
    int u = w * 16 + ul;                 // hidden unit (B n-index)
    int n0 = blockIdx.x * 16;

    f16x8 wih[12], whh[12];              // [gate*4 + ktile]
#pragma unroll
    for (int g = 0; g < 3; ++g)
#pragma unroll
        for (int kt = 0; kt < 4; ++kt) {
            size_t roff = (size_t)(u + g * 128) * 128 + kt * 32 + q * 8;
            wih[g * 4 + kt] = cvt8(W_ih + roff);
            whh[g * 4 + kt] = cvt8(W_hh + roff);
        }
    float bi0 = b_ih[u], bi1 = b_ih[u + 128], bi2 = b_ih[u + 256];
    float bh0 = b_hh[u], bh1 = b_hh[u + 128], bh2 = b_hh[u + 256];

    for (int idx = tid; idx < 16 * 136; idx += 512) hbuf[0][idx] = (_Float16)0.f;
    float hh[4] = {0.f, 0.f, 0.f, 0.f};
    __syncthreads();

    int p = 0;
    const f32x4 zero4 = {0.f, 0.f, 0.f, 0.f};
    for (int t = 0; t < 64; ++t) {
        // input A-frags (row n0+ul, k = kt*32 + q*8 + j)
        const _Float16* xr = xin + ((size_t)(n0 + ul) * 64 + t) * 128 + q * 8;
        f16x8 xf[4], hf[4];
#pragma unroll
        for (int kt = 0; kt < 4; ++kt) xf[kt] = *(const f16x8*)(xr + kt * 32);
        const _Float16* hb = &hbuf[p][ul * 136 + q * 8];
#pragma unroll
        for (int kt = 0; kt < 4; ++kt) hf[kt] = *(const f16x8*)(hb + kt * 32);

        f32x4 ax[3], ah[3];
#pragma unroll
        for (int g = 0; g < 3; ++g) { ax[g] = zero4; ah[g] = zero4; }
#pragma unroll
        for (int g = 0; g < 3; ++g)
#pragma unroll
            for (int kt = 0; kt < 4; ++kt) {
                ax[g] = __builtin_amdgcn_mfma_f32_16x16x32_f16(xf[kt], wih[g * 4 + kt], ax[g], 0, 0, 0);
                ah[g] = __builtin_amdgcn_mfma_f32_16x16x32_f16(hf[kt], whh[g * 4 + kt], ah[g], 0, 0, 0);
            }

        _Float16* wb = &hbuf[p ^ 1][0];
#pragma unroll
        for (int j = 0; j < 4; ++j) {  // C layout: row = q*4+j, col = ul (unit u)
            float rr = sigmoidf_(ax[0][j] + bi0 + ah[0][j] + bh0);
            float zz = sigmoidf_(ax[1][j] + bi1 + ah[1][j] + bh1);
            float nn = tanhf_(ax[2][j] + bi2 + rr * (ah[2][j] + bh2));
            float hn = (1.f - zz) * nn + zz * hh[j];
            hh[j] = hn;
            wb[(q * 4 + j) * 136 + u] = (_Float16)hn;
        }
        __syncthreads();
        p ^= 1;
        if (hout != nullptr && tid < 256) {
            int r2 = tid >> 4, seg = tid & 15;
            f16x8 v = *(const f16x8*)&hbuf[p][r2 * 136 + seg * 8];
            *(f16x8*)(hout + ((size_t)(n0 + r2) * 64 + t) * 128 + seg * 8) = v;
        }
    }
    if (es != nullptr) {
#pragma unroll
        for (int j = 0; j < 4; ++j)
            es[(size_t)(n0 + q * 4 + j) * 128 + u] = hh[j];
    }
}

// ---------------- Generic small matmul: out[n][o] = act(sum_k A[n][k]*W[o][k] + bias[o]) --------
// O in {128, 32}; W staged in LDS as f16 (k-dim is always 128).
__global__ __launch_bounds__(256) void k_mm(const float* __restrict__ A,
                                            const float* __restrict__ W,
                                            const float* __restrict__ bias,
                                            float* __restrict__ out,
                                            float* __restrict__ rowsum,
                                            int O, int act)
{
    __shared__ __align__(16) _Float16 Wls[128 * 136];
    int tid = threadIdx.x;
    int total = O * 128;
    for (int idx = tid; idx < total; idx += 256) {
        int o = idx >> 7, k = idx & 127;
        Wls[o * 136 + k] = (_Float16)W[idx];
    }
    __syncthreads();
    int o = tid & (O - 1);
    int r = tid / O;
    int R = 256 / O;
    size_t n = (size_t)blockIdx.x * R + r;
    const f32x4* Ap = (const f32x4*)(A + n * 128);
    float acc = bias ? bias[o] : 0.f;
#pragma unroll 4
    for (int k8 = 0; k8 < 16; ++k8) {
        f16x8 wv = *(const f16x8*)&Wls[o * 136 + k8 * 8];
        f32x4 a0 = Ap[k8 * 2], a1 = Ap[k8 * 2 + 1];
        acc += (float)wv[0] * a0[0] + (float)wv[1] * a0[1] + (float)wv[2] * a0[2] + (float)wv[3] * a0[3]
             + (float)wv[4] * a1[0] + (float)wv[5] * a1[1] + (float)wv[6] * a1[2] + (float)wv[7] * a1[3];
    }
    float v = acc;
    if (act == 1) v = lrelu_(v);
    else if (act == 2) v = sigmoidf_(v);
    out[n * O + o] = v;
    if (rowsum) {  // only used with O=32 (fits in a wave sub-group)
        float s = v;
#pragma unroll
        for (int m = 1; m < 32; m <<= 1) s += __shfl_xor(s, m);
        if (o == 0) rowsum[n] = s;
    }
}

// ---------------- m[j][:] += sum_n S[n][j]*X[n][:], d_e[j] += sum_n S[n][j] ----------------
__global__ __launch_bounds__(128) void k_edge_reduce(const void* __restrict__ S, int isInt,
                                                     const float* __restrict__ X,
                                                     float* __restrict__ m, float* __restrict__ d_e,
                                                     int E, int N, int chunk)
{
    int j = blockIdx.x;
    int n0 = blockIdx.y * chunk;
    int n1 = n0 + chunk; if (n1 > N) n1 = N;
    int c = threadIdx.x;
    float acc = 0.f, cnt = 0.f;
    const int* Si = (const int*)S; const float* Sf = (const float*)S;
    for (int n = n0; n < n1; ++n) {
        float s = isInt ? (float)Si[(size_t)n * E + j] : Sf[(size_t)n * E + j];
        acc += s * X[(size_t)n * 128 + c];
        cnt += s;
    }
    atomicAdd(&m[j * 128 + c], acc);
    if (c == 0) atomicAdd(&d_e[j], cnt);
}

__global__ void k_scale_m(float* __restrict__ m, const float* __restrict__ d_e)
{
    float d = d_e[blockIdx.x];
    float s = d > 0.f ? 1.f / d : 0.f;
    m[blockIdx.x * 128 + threadIdx.x] *= s;
}

// ---------------- outMain = lrelu((sum_j S[n][j]*m[j][c]) * scale(n) + bias[c]);
//                  outSub = base - outMain ----------------
__global__ __launch_bounds__(256) void k_hconv_apply(const void* __restrict__ S, int isInt, int E,
                                                     const float* __restrict__ m,
                                                     const float* __restrict__ dn_pre, int sqrtMode,
                                                     const float* __restrict__ bias,
                                                     const float* __restrict__ base,
                                                     float* __restrict__ outMain,
                                                     float* __restrict__ outSub)
{
    __shared__ float mls[64 * 128];
    int tid = threadIdx.x;
    for (int idx = tid; idx < E * 128; idx += 256) mls[idx] = m[idx];
    __syncthreads();
    int c = tid & 127, r = tid >> 7;
    size_t n = (size_t)blockIdx.x * 2 + r;
    const int* Si = (const int*)S; const float* Sf = (const float*)S;
    float acc = 0.f, d = 0.f;
    for (int j = 0; j < E; ++j) {
        float s = isInt ? (float)Si[n * E + j] : Sf[n * E + j];
        acc += s * mls[j * 128 + c];
        d += s;
    }
    if (dn_pre) d = dn_pre[n];
    float sc = d > 0.f ? (sqrtMode ? rsqrtf(d) : 1.f / d) : 0.f;
    float v = acc * sc + (bias ? bias[c] : 0.f);
    v = lrelu_(v);
    outMain[n * 128 + c] = v;
    if (outSub) outSub[n * 128 + c] = base[n * 128 + c] - v;
}

// ---------------- out[n] = [e_p|e_h|e_a] . Wf + bf ----------------
__global__ __launch_bounds__(256) void k_final(const float* __restrict__ ep,
                                               const float* __restrict__ eh,
                                               const float* __restrict__ ea,
                                               const float* __restrict__ Wf,
                                               const float* __restrict__ bf,
                                               float* __restrict__ out, int N)
{
    int wv = threadIdx.x >> 6, lane = threadIdx.x & 63;
    int n = blockIdx.x * 4 + wv;
    if (n >= N) return;
    size_t base = (size_t)n * 128;
    float acc = ep[base + lane] * Wf[lane]       + ep[base + lane + 64] * Wf[lane + 64]
              + eh[base + lane] * Wf[128 + lane] + eh[base + lane + 64] * Wf[128 + lane + 64]
              + ea[base + lane] * Wf[256 + lane] + ea[base + lane + 64] * Wf[256 + lane + 64];
#pragma unroll
    for (int m2 = 1; m2 < 64; m2 <<= 1) acc += __shfl_xor(acc, m2);
    if (lane == 0) out[n] = acc + bf[0];
}

extern "C" void kernel_launch(void* const* d_in, const int* in_sizes, int n_in,
                              void* d_out, int out_size, void* d_ws, size_t ws_size,
                              hipStream_t stream)
{
    const float* x     = (const float*)d_in[0];
    const int*   Hp    = (const int*)d_in[1];
    const float* ln_g  = (const float*)d_in[2];
    const float* ln_b  = (const float*)d_in[3];
    const float* W_ih0 = (const float*)d_in[4];
    const float* W_hh0 = (const float*)d_in[5];
    const float* b_ih0 = (const float*)d_in[6];
    const float* b_hh0 = (const float*)d_in[7];
    const float* W_ih1 = (const float*)d_in[8];
    const float* W_hh1 = (const float*)d_in[9];
    const float* b_ih1 = (const float*)d_in[10];
    const float* b_hh1 = (const float*)d_in[11];
    const float* Wp    = (const float*)d_in[12];
    const float* bp    = (const float*)d_in[13];
    const float* prot  = (const float*)d_in[14];
    const float* Ws    = (const float*)d_in[15];
    const float* bs    = (const float*)d_in[16];
    const float* Wa    = (const float*)d_in[17];
    const float* ba    = (const float*)d_in[18];
    const float* Wf    = (const float*)d_in[19];
    const float* bf    = (const float*)d_in[20];
    float* out = (float*)d_out;
    (void)n_in; (void)out_size; (void)ws_size;

    const int T = 64, F = 128, E = 64, K = 32;
    int N = in_sizes[0] / (T * F);           // 4000
    size_t NT = (size_t)N * T;

    char* ws = (char*)d_ws;
    size_t off = 0;
    auto alloc = [&](size_t bytes) { char* p = ws + off; off += (bytes + 255) & ~(size_t)255; return p; };
    _Float16* xn  = (_Float16*)alloc(NT * 128 * 2);
    _Float16* h1  = (_Float16*)alloc(NT * 128 * 2);
    float* e_s   = (float*)alloc((size_t)N * 128 * 4);
    float* t1    = (float*)alloc((size_t)N * 128 * 4);
    float* e_p   = (float*)alloc((size_t)N * 128 * 4);
    float* e_r   = (float*)alloc((size_t)N * 128 * 4);
    float* beta  = (float*)alloc((size_t)N * K * 4);
    float* dn2   = (float*)alloc((size_t)N * 4);
    float* xW    = (float*)alloc((size_t)N * 128 * 4);
    float* e_h   = (float*)alloc((size_t)N * 128 * 4);
    float* e_res = (float*)alloc((size_t)N * 128 * 4);
    float* e_al  = (float*)alloc((size_t)N * 128 * 4);
    float* macc  = (float*)alloc((64 * 128 + 64 + 32 * 128 + 32) * 4);
    float* m_e  = macc;
    float* d_e  = macc + 64 * 128;
    float* m2   = d_e + 64;
    float* d_e2 = m2 + 32 * 128;

    k_ln<<<(int)(NT / 16), 256, 0, stream>>>(x, ln_g, ln_b, xn);
    k_gru<<<N / 16, 512, 0, stream>>>(xn, W_ih0, W_hh0, b_ih0, b_hh0, h1, nullptr);
    k_gru<<<N / 16, 512, 0, stream>>>(h1, W_ih1, W_hh1, b_ih1, b_hh1, nullptr, e_s);

    k_mm<<<N / 2, 256, 0, stream>>>(e_s, Wp, nullptr, t1, nullptr, 128, 0);
    hipMemsetAsync(macc, 0, (64 * 128 + 64 + 32 * 128 + 32) * 4, stream);
    int chunk = (N + 7) / 8;
    k_edge_reduce<<<dim3(E, 8), 128, 0, stream>>>(Hp, 1, t1, m_e, d_e, E, N, chunk);
    k_scale_m<<<E, 128, 0, stream>>>(m_e, d_e);
    k_hconv_apply<<<N / 2, 256, 0, stream>>>(Hp, 1, E, m_e, nullptr, 0, bp, e_s, e_p, e_r);

    k_mm<<<N / 2, 256, 0, stream>>>(e_r, Ws, bs, xW, nullptr, 128, 0);
    k_mm<<<N / 8, 256, 0, stream>>>(e_r, prot, nullptr, beta, dn2, 32, 2);
    k_edge_reduce<<<dim3(K, 8), 128, 0, stream>>>(beta, 0, xW, m2, d_e2, K, N, chunk);
    k_scale_m<<<K, 128, 0, stream>>>(m2, d_e2);
    k_hconv_apply<<<N / 2, 256, 0, stream>>>(beta, 0, K, m2, dn2, 1, nullptr, e_r, e_h, e_res);

    k_mm<<<N / 2, 256, 0, stream>>>(e_res, Wa, ba, e_al, nullptr, 128, 1);
    k_final<<<(N + 3) / 4, 256, 0, stream>>>(e_p, e_h, e_al, Wf, bf, out, N);
}

// Round 2
// 811.421 us; speedup vs baseline: 1.3165x; 1.3165x over previous
//
#include <hip/hip_runtime.h>
#include <hip/hip_fp16.h>

typedef float    f32x4 __attribute__((ext_vector_type(4)));
typedef _Float16 f16x8 __attribute__((ext_vector_type(8)));

__device__ __forceinline__ float sigmoidf_(float x) { return 1.f / (1.f + __expf(-x)); }
__device__ __forceinline__ float tanhf_(float x) { float e = __expf(2.f * x); return 1.f - 2.f / (e + 1.f); }
__device__ __forceinline__ float lrelu_(float v) { return v > 0.f ? v : 0.01f * v; }

__device__ __forceinline__ f16x8 cvt8(const float* p) {
    const f32x4* q = (const f32x4*)p;
    f32x4 a = q[0], b = q[1];
    f16x8 v;
    v[0] = (_Float16)a[0]; v[1] = (_Float16)a[1]; v[2] = (_Float16)a[2]; v[3] = (_Float16)a[3];
    v[4] = (_Float16)b[0]; v[5] = (_Float16)b[1]; v[6] = (_Float16)b[2]; v[7] = (_Float16)b[3];
    return v;
}

// ---------------- LayerNorm + cast to f16, row-major [NT][128] ----------------
__global__ __launch_bounds__(256) void k_ln(const float* __restrict__ x,
                                            const float* __restrict__ g,
                                            const float* __restrict__ b,
                                            _Float16* __restrict__ xn)
{
    int tid = threadIdx.x;
    int r = tid >> 4, i = tid & 15;
    size_t row = (size_t)blockIdx.x * 16 + r;
    const f32x4* xp = (const f32x4*)(x + row * 128 + i * 8);
    f32x4 a0 = xp[0], a1 = xp[1];
    float v0=a0[0], v1=a0[1], v2=a0[2], v3=a0[3], v4=a1[0], v5=a1[1], v6=a1[2], v7=a1[3];
    float s  = v0+v1+v2+v3+v4+v5+v6+v7;
    float s2 = v0*v0+v1*v1+v2*v2+v3*v3+v4*v4+v5*v5+v6*v6+v7*v7;
#pragma unroll
    for (int m = 1; m <= 8; m <<= 1) { s += __shfl_xor(s, m); s2 += __shfl_xor(s2, m); }
    float mu  = s * (1.f / 128.f);
    float var = s2 * (1.f / 128.f) - mu * mu;
    float rs  = rsqrtf(var + 1e-5f);
    const f32x4* gp = (const f32x4*)(g + i * 8);
    const f32x4* bp = (const f32x4*)(b + i * 8);
    f32x4 g0 = gp[0], g1 = gp[1], bb0 = bp[0], bb1 = bp[1];
    f16x8 o;
    o[0] = (_Float16)((v0 - mu) * rs * g0[0] + bb0[0]);
    o[1] = (_Float16)((v1 - mu) * rs * g0[1] + bb0[1]);
    o[2] = (_Float16)((v2 - mu) * rs * g0[2] + bb0[2]);
    o[3] = (_Float16)((v3 - mu) * rs * g0[3] + bb0[3]);
    o[4] = (_Float16)((v4 - mu) * rs * g1[0] + bb1[0]);
    o[5] = (_Float16)((v5 - mu) * rs * g1[1] + bb1[1]);
    o[6] = (_Float16)((v6 - mu) * rs * g1[2] + bb1[2]);
    o[7] = (_Float16)((v7 - mu) * rs * g1[3] + bb1[3]);
    *(f16x8*)(xn + row * 128 + i * 8) = o;
}

// ---------------- Fused GRU layer ----------------
__global__ __launch_bounds__(512, 2) void k_gru(const _Float16* __restrict__ xin,
                                                const float* __restrict__ W_ih,
                                                const float* __restrict__ W_hh,
                                                const float* __restrict__ b_ih,
                                                const float* __restrict__ b_hh,
                                                _Float16* __restrict__ hout,
                                                float* __restrict__ es)
{
    __shared__ __align__(16) _Float16 hbuf[2][16 * 136];
    int tid = threadIdx.x;
    int w = tid >> 6, lane = tid & 63;
    int ul = lane & 15, q = lane >> 4;
    int u = w * 16 + ul;
    int n0 = blockIdx.x * 16;

    f16x8 wih[12], whh[12];
#pragma unroll
    for (int g = 0; g < 3; ++g)
#pragma unroll
        for (int kt = 0; kt < 4; ++kt) {
            size_t roff = (size_t)(u + g * 128) * 128 + kt * 32 + q * 8;
            wih[g * 4 + kt] = cvt8(W_ih + roff);
            whh[g * 4 + kt] = cvt8(W_hh + roff);
        }
    float bi0 = b_ih[u], bi1 = b_ih[u + 128], bi2 = b_ih[u + 256];
    float bh0 = b_hh[u], bh1 = b_hh[u + 128], bh2 = b_hh[u + 256];

    for (int idx = tid; idx < 16 * 136; idx += 512) hbuf[0][idx] = (_Float16)0.f;
    float hh[4] = {0.f, 0.f, 0.f, 0.f};
    __syncthreads();

    int p = 0;
    const f32x4 zero4 = {0.f, 0.f, 0.f, 0.f};
    for (int t = 0; t < 64; ++t) {
        const _Float16* xr = xin + ((size_t)(n0 + ul) * 64 + t) * 128 + q * 8;
        f16x8 xf[4], hf[4];
#pragma unroll
        for (int kt = 0; kt < 4; ++kt) xf[kt] = *(const f16x8*)(xr + kt * 32);
        const _Float16* hb = &hbuf[p][ul * 136 + q * 8];
#pragma unroll
        for (int kt = 0; kt < 4; ++kt) hf[kt] = *(const f16x8*)(hb + kt * 32);

        f32x4 ax[3], ah[3];
#pragma unroll
        for (int g = 0; g < 3; ++g) { ax[g] = zero4; ah[g] = zero4; }
#pragma unroll
        for (int g = 0; g < 3; ++g)
#pragma unroll
            for (int kt = 0; kt < 4; ++kt) {
                ax[g] = __builtin_amdgcn_mfma_f32_16x16x32_f16(xf[kt], wih[g * 4 + kt], ax[g], 0, 0, 0);
                ah[g] = __builtin_amdgcn_mfma_f32_16x16x32_f16(hf[kt], whh[g * 4 + kt], ah[g], 0, 0, 0);
            }

        _Float16* wb = &hbuf[p ^ 1][0];
#pragma unroll
        for (int j = 0; j < 4; ++j) {
            float rr = sigmoidf_(ax[0][j] + bi0 + ah[0][j] + bh0);
            float zz = sigmoidf_(ax[1][j] + bi1 + ah[1][j] + bh1);
            float nn = tanhf_(ax[2][j] + bi2 + rr * (ah[2][j] + bh2));
            float hn = (1.f - zz) * nn + zz * hh[j];
            hh[j] = hn;
            wb[(q * 4 + j) * 136 + u] = (_Float16)hn;
        }
        __syncthreads();
        p ^= 1;
        if (hout != nullptr && tid < 256) {
            int r2 = tid >> 4, seg = tid & 15;
            f16x8 v = *(const f16x8*)&hbuf[p][r2 * 136 + seg * 8];
            *(f16x8*)(hout + ((size_t)(n0 + r2) * 64 + t) * 128 + seg * 8) = v;
        }
    }
    if (es != nullptr) {
#pragma unroll
        for (int j = 0; j < 4; ++j)
            es[(size_t)(n0 + q * 4 + j) * 128 + u] = hh[j];
    }
}

// ---------------- Generic small matmul ----------------
__global__ __launch_bounds__(256) void k_mm(const float* __restrict__ A,
                                            const float* __restrict__ W,
                                            const float* __restrict__ bias,
                                            float* __restrict__ out,
                                            float* __restrict__ rowsum,
                                            int O, int act)
{
    __shared__ __align__(16) _Float16 Wls[128 * 136];
    int tid = threadIdx.x;
    int total = O * 128;
    for (int idx = tid; idx < total; idx += 256) {
        int o = idx >> 7, k = idx & 127;
        Wls[o * 136 + k] = (_Float16)W[idx];
    }
    __syncthreads();
    int o = tid & (O - 1);
    int r = tid / O;
    int R = 256 / O;
    size_t n = (size_t)blockIdx.x * R + r;
    const f32x4* Ap = (const f32x4*)(A + n * 128);
    float acc = bias ? bias[o] : 0.f;
#pragma unroll 4
    for (int k8 = 0; k8 < 16; ++k8) {
        f16x8 wv = *(const f16x8*)&Wls[o * 136 + k8 * 8];
        f32x4 a0 = Ap[k8 * 2], a1 = Ap[k8 * 2 + 1];
        acc += (float)wv[0] * a0[0] + (float)wv[1] * a0[1] + (float)wv[2] * a0[2] + (float)wv[3] * a0[3]
             + (float)wv[4] * a1[0] + (float)wv[5] * a1[1] + (float)wv[6] * a1[2] + (float)wv[7] * a1[3];
    }
    float v = acc;
    if (act == 1) v = lrelu_(v);
    else if (act == 2) v = sigmoidf_(v);
    out[n * O + o] = v;
    if (rowsum) {
        float s = v;
#pragma unroll
        for (int m = 1; m < 32; m <<= 1) s += __shfl_xor(s, m);
        if (o == 0) rowsum[n] = s;
    }
}

// ---------------- edge reduce, stage 1: blocked outer-product partials ----------------
// m[j][c] = sum_n S[n][j] * X[n][c].  Grid: P blocks x 256 thr; block owns rows
// [n0,n0+rowsPerBlk). Thread: c = tid&127, pair = tid>>7. JG = E/32.
//   JG==2: pair = j-group (j in [32*pair, 32*pair+32)), all rows.
//   JG==1: both pairs cover j in [0,32); pair 0 even rows, pair 1 odd rows.
// S value for j is fetched by lane (j&31) of each wave and broadcast via readlane.
// Partials: part[(blk*2+pair)][32][128]. d_e via atomics (waves 0,2; lanes<32).
__global__ __launch_bounds__(256) void k_edge_part(const void* __restrict__ S, int isInt,
                                                   const float* __restrict__ X,
                                                   float* __restrict__ part,
                                                   float* __restrict__ d_e,
                                                   int E, int N, int rowsPerBlk)
{
    int tid = threadIdx.x;
    int pair = tid >> 7, c = tid & 127, lane = tid & 63;
    int JG = E >> 5;
    int jg, rOff, rStep;
    if (JG == 2) { jg = pair; rOff = 0; rStep = 1; }
    else         { jg = 0;    rOff = pair; rStep = 2; }
    int n0 = blockIdx.x * rowsPerBlk;
    int n1 = n0 + rowsPerBlk; if (n1 > N) n1 = N;
    const int* Si = (const int*)S; const float* Sf = (const float*)S;
    int js = jg * 32 + (lane & 31);

    float acc[32];
#pragma unroll
    for (int i = 0; i < 32; ++i) acc[i] = 0.f;
    float dcnt = 0.f;

    for (int n = n0 + rOff; n < n1; n += rStep) {
        float sval = isInt ? (float)Si[(size_t)n * E + js] : Sf[(size_t)n * E + js];
        float xc = X[(size_t)n * 128 + c];
        dcnt += sval;
        int sv = __float_as_int(sval);
#pragma unroll
        for (int jj = 0; jj < 32; ++jj) {
            float s = __int_as_float(__builtin_amdgcn_readlane(sv, jj));
            acc[jj] += s * xc;
        }
    }
    float* pp = part + ((size_t)(blockIdx.x * 2 + pair) * 32) * 128;
#pragma unroll
    for (int jj = 0; jj < 32; ++jj)
        pp[(size_t)jj * 128 + c] = acc[jj];
    // d_e: one copy per (pair), lanes 0..31 of the c<64 wave of each pair
    int w = tid >> 6;
    if ((w & 1) == 0 && (lane & 32) == 0)
        atomicAdd(&d_e[jg * 32 + lane], dcnt);
}

// ---------------- edge reduce, stage 2: sum partials, scale by 1/d_e ----------------
__global__ __launch_bounds__(128) void k_edge_finish(const float* __restrict__ part,
                                                     const float* __restrict__ d_e,
                                                     float* __restrict__ m, int P, int JG)
{
    int j = blockIdx.x, c = threadIdx.x;
    float acc = 0.f;
    if (JG == 2) {
        int pair = j >> 5, jj = j & 31;
        for (int b = 0; b < P; ++b)
            acc += part[((size_t)(b * 2 + pair) * 32 + jj) * 128 + c];
    } else {
        for (int b = 0; b < 2 * P; ++b)
            acc += part[((size_t)b * 32 + j) * 128 + c];
    }
    float d = d_e[j];
    float s = d > 0.f ? 1.f / d : 0.f;
    m[j * 128 + c] = acc * s;
}

// ---------------- hconv apply ----------------
__global__ __launch_bounds__(256) void k_hconv_apply(const void* __restrict__ S, int isInt, int E,
                                                     const float* __restrict__ m,
                                                     const float* __restrict__ dn_pre, int sqrtMode,
                                                     const float* __restrict__ bias,
                                                     const float* __restrict__ base,
                                                     float* __restrict__ outMain,
                                                     float* __restrict__ outSub)
{
    __shared__ float mls[64 * 128];
    int tid = threadIdx.x;
    for (int idx = tid; idx < E * 128; idx += 256) mls[idx] = m[idx];
    __syncthreads();
    int c = tid & 127, r = tid >> 7;
    size_t n = (size_t)blockIdx.x * 2 + r;
    const int* Si = (const int*)S; const float* Sf = (const float*)S;
    float acc = 0.f, d = 0.f;
    for (int j = 0; j < E; ++j) {
        float s = isInt ? (float)Si[n * E + j] : Sf[n * E + j];
        acc += s * mls[j * 128 + c];
        d += s;
    }
    if (dn_pre) d = dn_pre[n];
    float sc = d > 0.f ? (sqrtMode ? rsqrtf(d) : 1.f / d) : 0.f;
    float v = acc * sc + (bias ? bias[c] : 0.f);
    v = lrelu_(v);
    outMain[n * 128 + c] = v;
    if (outSub) outSub[n * 128 + c] = base[n * 128 + c] - v;
}

// ---------------- final projection ----------------
__global__ __launch_bounds__(256) void k_final(const float* __restrict__ ep,
                                               const float* __restrict__ eh,
                                               const float* __restrict__ ea,
                                               const float* __restrict__ Wf,
                                               const float* __restrict__ bf,
                                               float* __restrict__ out, int N)
{
    int wv = threadIdx.x >> 6, lane = threadIdx.x & 63;
    int n = blockIdx.x * 4 + wv;
    if (n >= N) return;
    size_t base = (size_t)n * 128;
    float acc = ep[base + lane] * Wf[lane]       + ep[base + lane + 64] * Wf[lane + 64]
              + eh[base + lane] * Wf[128 + lane] + eh[base + lane + 64] * Wf[128 + lane + 64]
              + ea[base + lane] * Wf[256 + lane] + ea[base + lane + 64] * Wf[256 + lane + 64];
#pragma unroll
    for (int m2 = 1; m2 < 64; m2 <<= 1) acc += __shfl_xor(acc, m2);
    if (lane == 0) out[n] = acc + bf[0];
}

extern "C" void kernel_launch(void* const* d_in, const int* in_sizes, int n_in,
                              void* d_out, int out_size, void* d_ws, size_t ws_size,
                              hipStream_t stream)
{
    const float* x     = (const float*)d_in[0];
    const int*   Hp    = (const int*)d_in[1];
    const float* ln_g  = (const float*)d_in[2];
    const float* ln_b  = (const float*)d_in[3];
    const float* W_ih0 = (const float*)d_in[4];
    const float* W_hh0 = (const float*)d_in[5];
    const float* b_ih0 = (const float*)d_in[6];
    const float* b_hh0 = (const float*)d_in[7];
    const float* W_ih1 = (const float*)d_in[8];
    const float* W_hh1 = (const float*)d_in[9];
    const float* b_ih1 = (const float*)d_in[10];
    const float* b_hh1 = (const float*)d_in[11];
    const float* Wp    = (const float*)d_in[12];
    const float* bp    = (const float*)d_in[13];
    const float* prot  = (const float*)d_in[14];
    const float* Ws    = (const float*)d_in[15];
    const float* bs    = (const float*)d_in[16];
    const float* Wa    = (const float*)d_in[17];
    const float* ba    = (const float*)d_in[18];
    const float* Wf    = (const float*)d_in[19];
    const float* bf    = (const float*)d_in[20];
    float* out = (float*)d_out;
    (void)n_in; (void)out_size; (void)ws_size;

    const int T = 64, E = 64, K = 32;
    int N = in_sizes[0] / (T * 128);         // 4000
    size_t NT = (size_t)N * T;

    const int ROWS_PER_BLK = 16;
    int P = (N + ROWS_PER_BLK - 1) / ROWS_PER_BLK;   // 250

    char* ws = (char*)d_ws;
    size_t off = 0;
    auto alloc = [&](size_t bytes) { char* p = ws + off; off += (bytes + 255) & ~(size_t)255; return p; };
    _Float16* xn  = (_Float16*)alloc(NT * 128 * 2);
    _Float16* h1  = (_Float16*)alloc(NT * 128 * 2);
    float* e_s   = (float*)alloc((size_t)N * 128 * 4);
    float* t1    = (float*)alloc((size_t)N * 128 * 4);
    float* e_p   = (float*)alloc((size_t)N * 128 * 4);
    float* e_r   = (float*)alloc((size_t)N * 128 * 4);
    float* beta  = (float*)alloc((size_t)N * K * 4);
    float* dn2   = (float*)alloc((size_t)N * 4);
    float* xW    = (float*)alloc((size_t)N * 128 * 4);
    float* e_h   = (float*)alloc((size_t)N * 128 * 4);
    float* e_res = (float*)alloc((size_t)N * 128 * 4);
    float* e_al  = (float*)alloc((size_t)N * 128 * 4);
    float* part  = (float*)alloc((size_t)P * 2 * 32 * 128 * 4);   // 8 MB partials
    float* macc  = (float*)alloc((64 * 128 + 64 + 32 * 128 + 32) * 4);
    float* m_e  = macc;
    float* d_e  = macc + 64 * 128;
    float* m2   = d_e + 64;
    float* d_e2 = m2 + 32 * 128;

    k_ln<<<(int)(NT / 16), 256, 0, stream>>>(x, ln_g, ln_b, xn);
    k_gru<<<N / 16, 512, 0, stream>>>(xn, W_ih0, W_hh0, b_ih0, b_hh0, h1, nullptr);
    k_gru<<<N / 16, 512, 0, stream>>>(h1, W_ih1, W_hh1, b_ih1, b_hh1, nullptr, e_s);

    hipMemsetAsync(macc, 0, (64 * 128 + 64 + 32 * 128 + 32) * 4, stream);
    k_mm<<<N / 2, 256, 0, stream>>>(e_s, Wp, nullptr, t1, nullptr, 128, 0);
    k_edge_part<<<P, 256, 0, stream>>>(Hp, 1, t1, part, d_e, E, N, ROWS_PER_BLK);
    k_edge_finish<<<E, 128, 0, stream>>>(part, d_e, m_e, P, 2);
    k_hconv_apply<<<N / 2, 256, 0, stream>>>(Hp, 1, E, m_e, nullptr, 0, bp, e_s, e_p, e_r);

    k_mm<<<N / 2, 256, 0, stream>>>(e_r, Ws, bs, xW, nullptr, 128, 0);
    k_mm<<<N / 8, 256, 0, stream>>>(e_r, prot, nullptr, beta, dn2, 32, 2);
    k_edge_part<<<P, 256, 0, stream>>>(beta, 0, xW, part, d_e2, K, N, ROWS_PER_BLK);
    k_edge_finish<<<K, 128, 0, stream>>>(part, d_e2, m2, P, 1);
    k_hconv_apply<<<N / 2, 256, 0, stream>>>(beta, 0, K, m2, dn2, 1, nullptr, e_r, e_h, e_res);

    k_mm<<<N / 2, 256, 0, stream>>>(e_res, Wa, ba, e_al, nullptr, 128, 1);
    k_final<<<(N + 3) / 4, 256, 0, stream>>>(e_p, e_h, e_al, Wf, bf, out, N);
}